// Round 1
// baseline (392.676 us; speedup 1.0000x reference)
//
#include <hip/hip_runtime.h>

#define N_NODES 100000
#define N_EDGES 1600000
#define D_NODE 96
#define D_EDGE 32
#define N_GRAPHS 128
#define BN_EPS 1e-5f

#define EDGE_BLOCKS 1024
#define EDGE_THREADS 256

// ---------------- prep: fold BN into weights ----------------
// w1n[16][96]  = A[k] * W1[k][0:96]
// w1e[16][32]  = A[k] * W1[k][96:128]
// cw[0:16]  = C[k] = A[k]*(b1[k]-mean[k]) + beta[k]
// cw[16:32] = W2[k]
// cw[32]    = b2
__global__ void prep_kernel(const float* __restrict__ W1, const float* __restrict__ b1,
                            const float* __restrict__ gamma, const float* __restrict__ beta,
                            const float* __restrict__ rmean, const float* __restrict__ rvar,
                            const float* __restrict__ W2, const float* __restrict__ b2,
                            float* __restrict__ w1n, float* __restrict__ w1e,
                            float* __restrict__ cw) {
    int t = threadIdx.x;
    if (t < 16) {
        float A = gamma[t] * rsqrtf(rvar[t] + BN_EPS);
        cw[t] = A * (b1[t] - rmean[t]) + beta[t];
        cw[16 + t] = W2[t];
        for (int j = 0; j < D_NODE; ++j)
            w1n[t * D_NODE + j] = A * W1[t * (D_NODE + D_EDGE) + j];
        for (int j = 0; j < D_EDGE; ++j)
            w1e[t * D_EDGE + j] = A * W1[t * (D_NODE + D_EDGE) + D_NODE + j];
    }
    if (t == 16) cw[32] = b2[0];
}

// ---------------- node projection: y[n][k] = sum_i x[n][i]*w1n[k][i] ----------------
__global__ __launch_bounds__(256) void node_proj_kernel(const float* __restrict__ x,
                                                        const float* __restrict__ w1n,
                                                        float* __restrict__ y) {
    int n = blockIdx.x * 256 + threadIdx.x;
    if (n >= N_NODES) return;
    const float4* xr = (const float4*)(x + (size_t)n * D_NODE);
    float acc[16];
#pragma unroll
    for (int k = 0; k < 16; ++k) acc[k] = 0.f;
#pragma unroll
    for (int j4 = 0; j4 < D_NODE / 4; ++j4) {
        float4 xv = xr[j4];
#pragma unroll
        for (int k = 0; k < 16; ++k) {
            const float* w = w1n + k * D_NODE + j4 * 4;  // uniform address -> s_load
            acc[k] += xv.x * w[0] + xv.y * w[1] + xv.z * w[2] + xv.w * w[3];
        }
    }
    float4* yr = (float4*)(y + (size_t)n * 16);
#pragma unroll
    for (int q = 0; q < 4; ++q)
        yr[q] = make_float4(acc[q * 4 + 0], acc[q * 4 + 1], acc[q * 4 + 2], acc[q * 4 + 3]);
}

// ---------------- edge kernel: msg per edge, accumulate per-graph into LDS bins ----------------
__global__ __launch_bounds__(EDGE_THREADS) void edge_kernel(
    const float* __restrict__ ea, const int* __restrict__ eidx,
    const int* __restrict__ batch, const float* __restrict__ y,
    const float* __restrict__ w1e, const float* __restrict__ cw,
    float* __restrict__ partials) {
    __shared__ float bins[N_GRAPHS];
    int t = threadIdx.x;
    if (t < N_GRAPHS) bins[t] = 0.f;
    __syncthreads();

    const int* srcp = eidx;
    const int* dstp = eidx + N_EDGES;
    float b2v = cw[32];

    for (int e = blockIdx.x * EDGE_THREADS + t; e < N_EDGES; e += EDGE_BLOCKS * EDGE_THREADS) {
        int s = srcp[e];
        int d = dstp[e];

        const float4* er = (const float4*)(ea + (size_t)e * D_EDGE);
        float4 ev[8];
#pragma unroll
        for (int i = 0; i < 8; ++i) ev[i] = er[i];

        float ya[16];
        const float4* yr = (const float4*)(y + (size_t)s * 16);
#pragma unroll
        for (int q = 0; q < 4; ++q) ((float4*)ya)[q] = yr[q];

        float msg = b2v;
#pragma unroll
        for (int k = 0; k < 16; ++k) {
            float z = 0.f;
#pragma unroll
            for (int i = 0; i < 8; ++i) {
                const float* w = w1e + k * D_EDGE + i * 4;  // uniform -> s_load
                z += ev[i].x * w[0] + ev[i].y * w[1] + ev[i].z * w[2] + ev[i].w * w[3];
            }
            float h = z + ya[k] + cw[k];
            msg += fmaxf(h, 0.f) * cw[16 + k];
        }

        int g = batch[d];
        atomicAdd(&bins[g], msg);
    }

    __syncthreads();
    if (t < N_GRAPHS) partials[(size_t)blockIdx.x * N_GRAPHS + t] = bins[t];
}

// ---------------- final reduce: out[g] = sum_b partials[b][g] ----------------
__global__ __launch_bounds__(256) void reduce_kernel(const float* __restrict__ partials,
                                                     float* __restrict__ out) {
    __shared__ float s[256];
    int g = blockIdx.x;
    float acc = 0.f;
    for (int b = threadIdx.x; b < EDGE_BLOCKS; b += 256)
        acc += partials[(size_t)b * N_GRAPHS + g];
    s[threadIdx.x] = acc;
    __syncthreads();
    for (int w = 128; w > 0; w >>= 1) {
        if (threadIdx.x < w) s[threadIdx.x] += s[threadIdx.x + w];
        __syncthreads();
    }
    if (threadIdx.x == 0) out[g] = s[0];
}

extern "C" void kernel_launch(void* const* d_in, const int* in_sizes, int n_in,
                              void* d_out, int out_size, void* d_ws, size_t ws_size,
                              hipStream_t stream) {
    const float* x     = (const float*)d_in[0];
    const float* ea    = (const float*)d_in[1];
    const int*   eidx  = (const int*)d_in[2];
    const int*   batch = (const int*)d_in[3];
    const float* W1    = (const float*)d_in[4];
    const float* b1    = (const float*)d_in[5];
    const float* gamma = (const float*)d_in[6];
    const float* beta  = (const float*)d_in[7];
    const float* rmean = (const float*)d_in[8];
    const float* rvar  = (const float*)d_in[9];
    const float* W2    = (const float*)d_in[10];
    const float* b2    = (const float*)d_in[11];
    float* out = (float*)d_out;

    float* ws = (float*)d_ws;
    // ws layout (floats):
    float* w1n      = ws;                    // 16*96  = 1536
    float* w1e      = ws + 1536;             // 16*32  = 512
    float* cw       = ws + 2048;             // 33 (pad to 2048)
    float* y        = ws + 4096;             // N_NODES*16 = 1,600,000
    float* partials = ws + 4096 + (size_t)N_NODES * 16;  // EDGE_BLOCKS*128

    prep_kernel<<<1, 64, 0, stream>>>(W1, b1, gamma, beta, rmean, rvar, W2, b2, w1n, w1e, cw);
    node_proj_kernel<<<(N_NODES + 255) / 256, 256, 0, stream>>>(x, w1n, y);
    edge_kernel<<<EDGE_BLOCKS, EDGE_THREADS, 0, stream>>>(ea, eidx, batch, y, w1e, cw, partials);
    reduce_kernel<<<N_GRAPHS, 256, 0, stream>>>(partials, out);
}